// Round 1
// baseline (356.586 us; speedup 1.0000x reference)
//
#include <hip/hip_runtime.h>
#include <math.h>

// CapsuleRouting: u (8,144,16,16,12,12) f32, a (8,144,12,12) f32
// out: v (8,16,16,144) f32  ++  a_out (8,16,144) f32
//
// Restructured routing: r_i = a/C + agreement(u, V_i),  V_i = sum_{t<i} v_t.
// Per iteration: one streaming pass over u (S kernel, atomics into s),
// then squash + V update (Q kernel). Iter 0: softmax of constant = 1/16.

#define NB 8      // batch b
#define BDIM 144  // input capsules B
#define CDIM 16   // output capsules C
#define PDIM 16   // pose dim P2
#define SDIM 144  // spatial f*f = 12*12
#define PT 16     // spatial positions per tile
#define BC 16     // B values per chunk
#define NPT (SDIM / PT)  // 9
#define NBC (BDIM / BC)  // 9
#define VELEMS (NB * CDIM * PDIM * SDIM)  // 294912 (also v out size)
#define AELEMS (NB * CDIM * SDIM)         // 18432

__global__ __launch_bounds__(256) void s_kernel(const float* __restrict__ u,
                                                const float* __restrict__ a,
                                                const float* __restrict__ V,
                                                float* __restrict__ s,
                                                int iter) {
  // threads: pos = tid&15 (fast, coalesced), c = tid>>4
  __shared__ float Vt[CDIM][PDIM][PT];      // 16 KB, V tile (iter>0)
  __shared__ float lbuf[2][CDIM][PT + 1];   // ping-pong logits, padded

  const int tid = threadIdx.x;
  const int pos = tid & 15;
  const int c = tid >> 4;
  const int b = blockIdx.z;
  const int posg = blockIdx.y * PT + pos;
  const int B0 = blockIdx.x * BC;

  if (iter > 0) {
    const int vb = ((b * CDIM + c) * PDIM) * SDIM + posg;
#pragma unroll
    for (int p = 0; p < PDIM; ++p) Vt[c][p][pos] = V[vb + p * SDIM];
  }
  __syncthreads();

  float sacc[PDIM];
#pragma unroll
  for (int p = 0; p < PDIM; ++p) sacc[p] = 0.f;

  for (int Bi = B0; Bi < B0 + BC; ++Bi) {
    // load u[b][Bi][c][p][posg] for all p: 16 scalar loads, 64B runs per 16 lanes
    float uv[PDIM];
    const float* ub = u + ((size_t)((b * BDIM + Bi) * CDIM + c) * PDIM) * SDIM + posg;
#pragma unroll
    for (int p = 0; p < PDIM; ++p) uv[p] = ub[p * SDIM];

    float w;
    if (iter == 0) {
      // r constant over C -> softmax uniform
      w = 1.0f / CDIM;
    } else {
      float dot = 0.f;
#pragma unroll
      for (int p = 0; p < PDIM; ++p) dot += uv[p] * Vt[c][p][pos];
      const float logit = a[(b * BDIM + Bi) * SDIM + posg] * (1.0f / CDIM) + dot;
      const int pb = Bi & 1;  // ping-pong: 1 barrier per B (WAR covered by next B's barrier)
      lbuf[pb][c][pos] = logit;
      __syncthreads();
      float m = -1e30f;
#pragma unroll
      for (int c2 = 0; c2 < CDIM; ++c2) m = fmaxf(m, lbuf[pb][c2][pos]);
      float sum = 0.f;
#pragma unroll
      for (int c2 = 0; c2 < CDIM; ++c2) sum += __expf(lbuf[pb][c2][pos] - m);
      w = __expf(logit - m) / sum;
    }
#pragma unroll
    for (int p = 0; p < PDIM; ++p) sacc[p] += w * uv[p];
  }

  const int sb = ((b * CDIM + c) * PDIM) * SDIM + posg;
#pragma unroll
  for (int p = 0; p < PDIM; ++p) atomicAdd(&s[sb + p * SDIM], sacc[p]);
}

__global__ __launch_bounds__(256) void q_kernel(float* __restrict__ s,
                                                float* __restrict__ V,
                                                float* __restrict__ out_v,
                                                float* __restrict__ out_a,
                                                int iter) {
  // one thread per (b, c, posg): 18432 = 72 blocks * 256
  const int gid = blockIdx.x * 256 + threadIdx.x;
  const int b = gid / (CDIM * SDIM);
  const int rem = gid - b * (CDIM * SDIM);
  const int c = rem / SDIM;
  const int posg = rem - c * SDIM;
  const int base = ((b * CDIM + c) * PDIM) * SDIM + posg;

  float sv[PDIM];
  float sn = 0.f;
#pragma unroll
  for (int p = 0; p < PDIM; ++p) {
    const float x = s[base + p * SDIM];
    sv[p] = x;
    sn += x * x;
  }
  const float scale = sn / (1.0f + sn) * rsqrtf(sn);

  if (iter < 2) {
#pragma unroll
    for (int p = 0; p < PDIM; ++p) {
      V[base + p * SDIM] += sv[p] * scale;
      s[base + p * SDIM] = 0.f;  // re-zero for next iteration's atomics (saves a memset)
    }
  } else {
    float vv = 0.f;
#pragma unroll
    for (int p = 0; p < PDIM; ++p) {
      const float v = sv[p] * scale;
      out_v[base + p * SDIM] = v;
      vv += v * v;
    }
    out_a[gid] = sqrtf(vv);  // = ||v|| like reference
  }
}

extern "C" void kernel_launch(void* const* d_in, const int* in_sizes, int n_in,
                              void* d_out, int out_size, void* d_ws, size_t ws_size,
                              hipStream_t stream) {
  const float* u = (const float*)d_in[0];
  const float* a = (const float*)d_in[1];
  float* V = (float*)d_ws;            // accumulated sum of v over past iterations
  float* s = V + VELEMS;              // current-iteration weighted sum (atomic target)
  float* out_v = (float*)d_out;
  float* out_a = out_v + VELEMS;

  // ws is re-poisoned before every call: zero V and s (2 * 1.18 MB)
  hipMemsetAsync(d_ws, 0, (size_t)2 * VELEMS * sizeof(float), stream);

  const dim3 gS(NBC, NPT, NB);  // 9 x 9 x 8 = 648 blocks
  for (int it = 0; it < 3; ++it) {
    s_kernel<<<gS, 256, 0, stream>>>(u, a, V, s, it);
    q_kernel<<<AELEMS / 256, 256, 0, stream>>>(s, V, out_v, out_a, it);
  }
}

// Round 2
// 355.287 us; speedup vs baseline: 1.0037x; 1.0037x over previous
//
#include <hip/hip_runtime.h>
#include <math.h>

// CapsuleRouting: u (8,144,16,16,12,12) f32, a (8,144,12,12) f32
// out: v (8,16,16,144) f32  ++  a_out (8,16,144) f32
//
// r_i = a/C + agreement(u, V_i), V_i = sum_{t<i} v_t  (agreement linear in v)
// => never materialize r; one streaming pass over u per iteration.
// Iter 0: softmax of a constant over C => uniform 1/16 (pure streaming sum).
// Iters 1,2: single-exp no-max softmax via LDS (logits are O(10), fp32-safe),
// next-B loads double-buffered across the barrier.

#define NB 8
#define BDIM 144
#define CDIM 16
#define PDIM 16
#define SDIM 144
#define PT 16
#define BC 8                 // B per chunk
#define NPT (SDIM / PT)      // 9
#define NBC (BDIM / BC)      // 18
#define USTRIDE (CDIM * PDIM * SDIM)      // floats between consecutive B
#define VELEMS (NB * CDIM * PDIM * SDIM)  // 294912
#define AELEMS (NB * CDIM * SDIM)         // 18432

__global__ __launch_bounds__(256) void s_kernel(const float* __restrict__ u,
                                                const float* __restrict__ a,
                                                const float* __restrict__ V,
                                                float* __restrict__ s,
                                                int iter) {
  __shared__ float Vt[CDIM][PDIM][PT];     // 16 KB
  __shared__ float ebuf[2][CDIM][PT + 1];  // exp(logit) ping-pong, padded
  __shared__ float atile[BC][PT];          // a * (1/C)

  const int tid = threadIdx.x;
  const int pos = tid & 15;       // fast -> coalesced (64B runs per 16 lanes)
  const int c = tid >> 4;
  const int b = blockIdx.z;
  const int posg = blockIdx.y * PT + pos;
  const int B0 = blockIdx.x * BC;

  const float* ubase =
      u + ((size_t)((b * BDIM + B0) * CDIM + c) * PDIM) * SDIM + posg;

  float sacc[PDIM];
#pragma unroll
  for (int p = 0; p < PDIM; ++p) sacc[p] = 0.f;

  if (iter == 0) {
    // uniform weights: pure streaming sum over the B chunk
#pragma unroll 2
    for (int j = 0; j < BC; ++j) {
      const float* ub = ubase + (size_t)j * USTRIDE;
#pragma unroll
      for (int p = 0; p < PDIM; ++p) sacc[p] += ub[p * SDIM];
    }
    const int sb = ((b * CDIM + c) * PDIM) * SDIM + posg;
#pragma unroll
    for (int p = 0; p < PDIM; ++p)
      atomicAdd(&s[sb + p * SDIM], sacc[p] * (1.0f / CDIM));
    return;
  }

  // stage V tile and a tile
  {
    const int vb = ((b * CDIM + c) * PDIM) * SDIM + posg;
#pragma unroll
    for (int p = 0; p < PDIM; ++p) Vt[c][p][pos] = V[vb + p * SDIM];
    if (tid < BC * PT) {
      const int j = tid >> 4;  // pos = tid & 15
      atile[j][pos] =
          a[(b * BDIM + B0 + j) * SDIM + blockIdx.y * PT + pos] * (1.0f / CDIM);
    }
  }
  __syncthreads();

  float uvbuf[2][PDIM];
#pragma unroll
  for (int p = 0; p < PDIM; ++p) uvbuf[0][p] = ubase[p * SDIM];  // prologue j=0

#pragma unroll
  for (int j = 0; j < BC; ++j) {
    float* uv = uvbuf[j & 1];
    float* uvn = uvbuf[(j + 1) & 1];
    if (j + 1 < BC) {  // issue next-B loads BEFORE the barrier (overlap stall)
      const float* ub = ubase + (size_t)(j + 1) * USTRIDE;
#pragma unroll
      for (int p = 0; p < PDIM; ++p) uvn[p] = ub[p * SDIM];
    }
    float dot = 0.f;
#pragma unroll
    for (int p = 0; p < PDIM; ++p) dot += uv[p] * Vt[c][p][pos];
    const float e = __expf(atile[j][pos] + dot);  // no-max softmax: |logit|~O(10)
    ebuf[j & 1][c][pos] = e;
    __syncthreads();
    float sum = 0.f;
#pragma unroll
    for (int c2 = 0; c2 < CDIM; ++c2) sum += ebuf[j & 1][c2][pos];
    const float w = e * __builtin_amdgcn_rcpf(sum);
#pragma unroll
    for (int p = 0; p < PDIM; ++p) sacc[p] += w * uv[p];
    // WAR on ebuf[j&1] is covered by barrier j+1 (ping-pong)
  }

  const int sb = ((b * CDIM + c) * PDIM) * SDIM + posg;
#pragma unroll
  for (int p = 0; p < PDIM; ++p) atomicAdd(&s[sb + p * SDIM], sacc[p]);
}

__global__ __launch_bounds__(256) void q_kernel(float* __restrict__ s,
                                                float* __restrict__ V,
                                                float* __restrict__ out_v,
                                                float* __restrict__ out_a,
                                                int iter) {
  // one thread per (b, c, posg): 18432 = 72 blocks * 256
  const int gid = blockIdx.x * 256 + threadIdx.x;
  const int b = gid / (CDIM * SDIM);
  const int rem = gid - b * (CDIM * SDIM);
  const int c = rem / SDIM;
  const int posg = rem - c * SDIM;
  const int base = ((b * CDIM + c) * PDIM) * SDIM + posg;

  float sv[PDIM];
  float sn = 0.f;
#pragma unroll
  for (int p = 0; p < PDIM; ++p) {
    const float x = s[base + p * SDIM];
    sv[p] = x;
    sn += x * x;
  }
  const float scale = sn / (1.0f + sn) * rsqrtf(sn);

  if (iter < 2) {
#pragma unroll
    for (int p = 0; p < PDIM; ++p) {
      V[base + p * SDIM] += sv[p] * scale;
      s[base + p * SDIM] = 0.f;  // re-zero for next iteration's atomics
    }
  } else {
    float vv = 0.f;
#pragma unroll
    for (int p = 0; p < PDIM; ++p) {
      const float v = sv[p] * scale;
      out_v[base + p * SDIM] = v;
      vv += v * v;
    }
    out_a[gid] = sqrtf(vv);
  }
}

extern "C" void kernel_launch(void* const* d_in, const int* in_sizes, int n_in,
                              void* d_out, int out_size, void* d_ws, size_t ws_size,
                              hipStream_t stream) {
  const float* u = (const float*)d_in[0];
  const float* a = (const float*)d_in[1];
  float* V = (float*)d_ws;
  float* s = V + VELEMS;
  float* out_v = (float*)d_out;
  float* out_a = out_v + VELEMS;

  hipMemsetAsync(d_ws, 0, (size_t)2 * VELEMS * sizeof(float), stream);

  const dim3 gS(NBC, NPT, NB);  // 18 x 9 x 8 = 1296 blocks
  for (int it = 0; it < 3; ++it) {
    s_kernel<<<gS, 256, 0, stream>>>(u, a, V, s, it);
    q_kernel<<<AELEMS / 256, 256, 0, stream>>>(s, V, out_v, out_a, it);
  }
}